// Round 4
// baseline (211.114 us; speedup 1.0000x reference)
//
#include <hip/hip_runtime.h>
#include <math.h>

// Tsit5 tableau
#define A21f 0.161f
#define A31f -0.008480655492356989f
#define A32f 0.335480655492357f
#define A41f 2.8971530571054935f
#define A42f -6.359448489975075f
#define A43f 4.3622954328695815f
#define A51f 5.325864828439257f
#define A52f -11.748883564062828f
#define A53f 7.4955393428898365f
#define A54f -0.09249506636175525f
#define A61f 5.86145544294642f
#define A62f -12.92096931784711f
#define A63f 8.159367898576159f
#define A64f -0.071584973281401f
#define A65f -0.028269050394068383f
#define B1f 0.09646076681806523f
#define B2f 0.01f
#define B3f 0.4798896504144996f
#define B4f 1.379008574103742f
#define B5f -3.290069515436081f
#define B6f 2.324710524099774f
#define E1f -0.00178001105222577714f
#define E2f -0.0008164344596567469f
#define E3f 0.007880878010261995f
#define E4f -0.1447110071732629f
#define E5f 0.5823571654525552f
#define E6f -0.45808210592918697f
#define E7f 0.015151515151515152f

#define WPB 4  // waves per block

// DPP row_ror:k within each 16-lane row (VALU pipe — replaces LDS broadcast)
template<int CTRL>
__device__ __forceinline__ float rr(float v) {
    return __int_as_float(__builtin_amdgcn_mov_dpp(__float_as_int(v), CTRL, 0xf, 0xf, true));
}

// acc += dot over 16 rotated lanes: W[k] pre-gathered so that
// W[k] * (row_ror:k of v) is the matching matrix element.
#define DOT16(acc, W, v) do {                         \
    acc = fmaf((W)[0],  (v),          acc);           \
    acc = fmaf((W)[1],  rr<0x121>(v), acc);           \
    acc = fmaf((W)[2],  rr<0x122>(v), acc);           \
    acc = fmaf((W)[3],  rr<0x123>(v), acc);           \
    acc = fmaf((W)[4],  rr<0x124>(v), acc);           \
    acc = fmaf((W)[5],  rr<0x125>(v), acc);           \
    acc = fmaf((W)[6],  rr<0x126>(v), acc);           \
    acc = fmaf((W)[7],  rr<0x127>(v), acc);           \
    acc = fmaf((W)[8],  rr<0x128>(v), acc);           \
    acc = fmaf((W)[9],  rr<0x129>(v), acc);           \
    acc = fmaf((W)[10], rr<0x12A>(v), acc);           \
    acc = fmaf((W)[11], rr<0x12B>(v), acc);           \
    acc = fmaf((W)[12], rr<0x12C>(v), acc);           \
    acc = fmaf((W)[13], rr<0x12D>(v), acc);           \
    acc = fmaf((W)[14], rr<0x12E>(v), acc);           \
    acc = fmaf((W)[15], rr<0x12F>(v), acc);           \
} while (0)

// softplus(x) = max(x,0) + ln2 * log2(1 + 2^(-|x|*log2e))  (hw exp2/log2)
__device__ __forceinline__ float sp(float x) {
    float t = exp2f(-fabsf(x) * 1.44269504088896341f);
    return fmaxf(x, 0.0f) + 0.69314718055994531f * __log2f(1.0f + t);
}

__global__ __launch_bounds__(256)
__attribute__((amdgpu_waves_per_eu(4, 4)))
void ode_kernel(const float* __restrict__ x0s,
                const float* __restrict__ W1, const float* __restrict__ b1,
                const float* __restrict__ W2, const float* __restrict__ b2,
                const float* __restrict__ W3, const float* __restrict__ b3,
                const void* __restrict__ Tptr,
                float* __restrict__ out, int out_size, int B)
{
    const int wave = threadIdx.x >> 6;
    const int lane = threadIdx.x & 63;
    const int traj = blockIdx.x * WPB + wave;
    if (traj >= B) return;

    const int p = lane & 15;   // position within 16-lane DPP row
    const int g = lane >> 4;   // row-group 0..3
    const int godd = g & 1;
    const int jh = g >> 1;     // layer-2 input half

    // ---- one-time per-lane weight gathers in DPP-rotated order ----
    // L1 round A: row p,     input col 16g + (p+k)%16
    // L1 round B: row 16+p,  same cols
    float W1a[16], W1b[16], W2r[16], W3a[16], W3b[16];
    const int r2 = p + 16 * godd;
#pragma unroll
    for (int k = 0; k < 16; ++k) {
        const int c = (p + k) & 15;
        W1a[k] = W1[p * 64 + 16 * g + c];
        W1b[k] = W1[(16 + p) * 64 + 16 * g + c];
        W2r[k] = W2[r2 * 32 + 16 * jh + c];
        W3a[k] = W3[lane * 32 + c];
        W3b[k] = W3[lane * 32 + 16 + c];
    }
#pragma unroll
    for (int k = 0; k < 16; ++k) {
        asm("" : "+v"(W1a[k]));
        asm("" : "+v"(W1b[k]));
        asm("" : "+v"(W2r[k]));
        asm("" : "+v"(W3a[k]));
        asm("" : "+v"(W3b[k]));
    }
    const float b1a = b1[p], b1b = b1[p + 16];
    const float b2r = b2[r2], b3r = b3[lane];

    // f(u): u distributed lane-wise (lane i holds u[i]); result distributed.
    auto f = [&](float u) -> float {
        // layer 1: 64 -> 32
        float a1a = 0.f, a1b = 0.f;
        DOT16(a1a, W1a, u);
        DOT16(a1b, W1b, u);
        a1a += __shfl_xor(a1a, 16);
        a1a += __shfl_xor(a1a, 32);
        a1b += __shfl_xor(a1b, 16);
        a1b += __shfl_xor(a1b, 32);
        float h1A = sp(a1a + b1a);   // h1[p]    (replicated x4)
        float h1B = sp(a1b + b1b);   // h1[16+p]
        // layer 2: 32 -> 32  (this lane handles row r2, input half jh)
        float S = jh ? h1B : h1A;
        float a2 = 0.f;
        DOT16(a2, W2r, S);
        a2 += __shfl_xor(a2, 32);
        float h2v = sp(a2 + b2r);          // h2[r2] (replicated x2)
        float other = __shfl_xor(h2v, 16); // h2[p + 16*!godd]
        float h2A = godd ? other : h2v;    // h2[p]
        float h2B = godd ? h2v : other;    // h2[16+p]
        // layer 3: 32 -> 64, both halves combined in-lane
        float a3 = 0.f;
        DOT16(a3, W3a, h2A);
        DOT16(a3, W3b, h2B);
        return a3 + b3r;
    };

    int ti = *(const int*)Tptr;
    float Tf = (ti > 0 && ti < 1000000) ? (float)ti : *(const float*)Tptr;
    const float ts_step = Tf / 10.0f;

    float y = x0s[traj * 64 + lane];
    out[traj * 704 + lane] = y;

    float t = 0.0f;
    float dt = 1e-3f;
    int n = 0;

    float k1 = f(y);  // FSAL seed

    for (int iv = 1; iv <= 10; ++iv) {
        const float t_target = (iv == 10) ? Tf : ts_step * (float)iv;
        for (int it = 0; it < 64; ++it) {
            const float remaining = t_target - t;
            if (remaining <= 1e-12f) break;
            const float h = fminf(dt, fmaxf(remaining, 0.0f));

            float k2 = f(y + h * (A21f * k1));
            float k3 = f(y + h * (A31f * k1 + A32f * k2));
            float k4 = f(y + h * (A41f * k1 + A42f * k2 + A43f * k3));
            float k5 = f(y + h * (A51f * k1 + A52f * k2 + A53f * k3 + A54f * k4));
            float k6 = f(y + h * (A61f * k1 + A62f * k2 + A63f * k3 + A64f * k4 + A65f * k5));
            float y5 = y + h * (B1f * k1 + B2f * k2 + B3f * k3 + B4f * k4 + B5f * k5 + B6f * k6);
            float k7 = f(y5);
            float err = h * (E1f * k1 + E2f * k2 + E3f * k3 + E4f * k4 + E5f * k5 + E6f * k6 + E7f * k7);

            float scale = 1e-6f + 1e-3f * fmaxf(fabsf(y), fabsf(y5));
            float r = err / scale;
            float s = r * r;
#pragma unroll
            for (int m = 32; m >= 1; m >>= 1) s += __shfl_xor(s, m);
            float enorm = fmaxf(sqrtf(s * (1.0f / 64.0f)), 1e-10f);

            bool accept = enorm <= 1.0f;
            float fac = 0.9f * exp2f(-0.2f * __log2f(enorm));  // 0.9 * enorm^-0.2
            fac = fminf(fmaxf(fac, 0.1f), 5.0f);

            if (accept) { t += h; y = y5; k1 = k7; }
            dt = fmaxf(h * fac, 1e-8f);
            ++n;
        }
        out[traj * 704 + iv * 64 + lane] = y;
    }

    if (lane == 0) atomicAdd(out + (out_size - 1), (float)n);
}

__global__ void init_n(float* p) { *p = 0.0f; }

extern "C" void kernel_launch(void* const* d_in, const int* in_sizes, int n_in,
                              void* d_out, int out_size, void* d_ws, size_t ws_size,
                              hipStream_t stream) {
    const float* x0s = (const float*)d_in[0];
    const float* W1  = (const float*)d_in[1];
    const float* b1  = (const float*)d_in[2];
    const float* W2  = (const float*)d_in[3];
    const float* b2  = (const float*)d_in[4];
    const float* W3  = (const float*)d_in[5];
    const float* b3  = (const float*)d_in[6];
    const void*  Tp  = d_in[7];
    float* out = (float*)d_out;

    const int B = in_sizes[0] / 64;
    const int grid = (B + WPB - 1) / WPB;

    init_n<<<1, 1, 0, stream>>>(out + (out_size - 1));
    ode_kernel<<<grid, 256, 0, stream>>>(x0s, W1, b1, W2, b2, W3, b3, Tp,
                                         out, out_size, B);
}

// Round 5
// 191.296 us; speedup vs baseline: 1.1036x; 1.1036x over previous
//
#include <hip/hip_runtime.h>
#include <math.h>

// Tsit5 tableau
#define A21f 0.161f
#define A31f -0.008480655492356989f
#define A32f 0.335480655492357f
#define A41f 2.8971530571054935f
#define A42f -6.359448489975075f
#define A43f 4.3622954328695815f
#define A51f 5.325864828439257f
#define A52f -11.748883564062828f
#define A53f 7.4955393428898365f
#define A54f -0.09249506636175525f
#define A61f 5.86145544294642f
#define A62f -12.92096931784711f
#define A63f 8.159367898576159f
#define A64f -0.071584973281401f
#define A65f -0.028269050394068383f
#define B1f 0.09646076681806523f
#define B2f 0.01f
#define B3f 0.4798896504144996f
#define B4f 1.379008574103742f
#define B5f -3.290069515436081f
#define B6f 2.324710524099774f
#define E1f -0.00178001105222577714f
#define E2f -0.0008164344596567469f
#define E3f 0.007880878010261995f
#define E4f -0.1447110071732629f
#define E5f 0.5823571654525552f
#define E6f -0.45808210592918697f
#define E7f 0.015151515151515152f

#define WPB 4  // waves per block

// Fused rotate+FMA: acc += (row_ror:N of v) * w — ONE VALU inst (VOP2 DPP).
// Round-4 emitted separate v_mov_dpp + v_fmac (compiler didn't combine);
// this halves the per-dot instruction count.
#define FMAC_RR(acc, v, w, N)                                              \
    asm("v_fmac_f32_dpp %0, %1, %2 row_ror:" #N " row_mask:0xf bank_mask:0xf" \
        : "+v"(acc) : "v"(v), "v"(w))

// acc += 16-element dot; W[k] pre-gathered so W[k]*(row_ror:k of v) matches.
#define DOT16(acc, W, v) do {            \
    acc = fmaf((W)[0], (v), acc);        \
    FMAC_RR(acc, v, (W)[1], 1);          \
    FMAC_RR(acc, v, (W)[2], 2);          \
    FMAC_RR(acc, v, (W)[3], 3);          \
    FMAC_RR(acc, v, (W)[4], 4);          \
    FMAC_RR(acc, v, (W)[5], 5);          \
    FMAC_RR(acc, v, (W)[6], 6);          \
    FMAC_RR(acc, v, (W)[7], 7);          \
    FMAC_RR(acc, v, (W)[8], 8);          \
    FMAC_RR(acc, v, (W)[9], 9);          \
    FMAC_RR(acc, v, (W)[10], 10);        \
    FMAC_RR(acc, v, (W)[11], 11);        \
    FMAC_RR(acc, v, (W)[12], 12);        \
    FMAC_RR(acc, v, (W)[13], 13);        \
    FMAC_RR(acc, v, (W)[14], 14);        \
    FMAC_RR(acc, v, (W)[15], 15);        \
} while (0)

// softplus(x) = max(x,0) + ln2 * log2(1 + 2^(-|x|*log2e))  (hw exp2/log2)
__device__ __forceinline__ float sp(float x) {
    float t = exp2f(-fabsf(x) * 1.44269504088896341f);
    return fmaxf(x, 0.0f) + 0.69314718055994531f * __log2f(1.0f + t);
}

__global__ __launch_bounds__(256)
__attribute__((amdgpu_waves_per_eu(4, 4)))
void ode_kernel(const float* __restrict__ x0s,
                const float* __restrict__ W1, const float* __restrict__ b1,
                const float* __restrict__ W2, const float* __restrict__ b2,
                const float* __restrict__ W3, const float* __restrict__ b3,
                const void* __restrict__ Tptr,
                float* __restrict__ out, int out_size, int B)
{
    const int wave = threadIdx.x >> 6;
    const int lane = threadIdx.x & 63;
    const int traj = blockIdx.x * WPB + wave;
    if (traj >= B) return;

    const int p = lane & 15;   // position within 16-lane DPP row
    const int g = lane >> 4;   // row-group 0..3
    const int godd = g & 1;
    const int jh = g >> 1;     // layer-2 input half

    // ---- one-time per-lane weight gathers in DPP-rotated order ----
    float W1a[16], W1b[16], W2r[16], W3a[16], W3b[16];
    const int r2 = p + 16 * godd;
#pragma unroll
    for (int k = 0; k < 16; ++k) {
        const int c = (p + k) & 15;
        W1a[k] = W1[p * 64 + 16 * g + c];
        W1b[k] = W1[(16 + p) * 64 + 16 * g + c];
        W2r[k] = W2[r2 * 32 + 16 * jh + c];
        W3a[k] = W3[lane * 32 + c];
        W3b[k] = W3[lane * 32 + 16 + c];
    }
#pragma unroll
    for (int k = 0; k < 16; ++k) {
        asm("" : "+v"(W1a[k]));
        asm("" : "+v"(W1b[k]));
        asm("" : "+v"(W2r[k]));
        asm("" : "+v"(W3a[k]));
        asm("" : "+v"(W3b[k]));
    }
    const float b1a = b1[p], b1b = b1[p + 16];
    const float b2r = b2[r2], b3r = b3[lane];

    // f(u): u distributed lane-wise (lane i holds u[i]); result distributed.
    auto f = [&](float u) -> float {
        // layer 1: 64 -> 32
        float a1a = 0.f, a1b = 0.f;
        DOT16(a1a, W1a, u);
        DOT16(a1b, W1b, u);
        a1a += __shfl_xor(a1a, 16);
        a1a += __shfl_xor(a1a, 32);
        a1b += __shfl_xor(a1b, 16);
        a1b += __shfl_xor(a1b, 32);
        float h1A = sp(a1a + b1a);   // h1[p]    (replicated x4)
        float h1B = sp(a1b + b1b);   // h1[16+p]
        // layer 2: 32 -> 32  (this lane handles row r2, input half jh)
        float S = jh ? h1B : h1A;
        float a2 = 0.f;
        DOT16(a2, W2r, S);
        a2 += __shfl_xor(a2, 32);
        float h2v = sp(a2 + b2r);          // h2[r2] (replicated x2)
        float other = __shfl_xor(h2v, 16); // h2[p + 16*!godd]
        float h2A = godd ? other : h2v;    // h2[p]
        float h2B = godd ? h2v : other;    // h2[16+p]
        // layer 3: 32 -> 64, both halves combined in-lane
        float a3 = 0.f;
        DOT16(a3, W3a, h2A);
        DOT16(a3, W3b, h2B);
        return a3 + b3r;
    };

    int ti = *(const int*)Tptr;
    float Tf = (ti > 0 && ti < 1000000) ? (float)ti : *(const float*)Tptr;
    const float ts_step = Tf / 10.0f;

    float y = x0s[traj * 64 + lane];
    out[traj * 704 + lane] = y;

    float t = 0.0f;
    float dt = 1e-3f;
    int n = 0;

    float k1 = f(y);  // FSAL seed

    for (int iv = 1; iv <= 10; ++iv) {
        const float t_target = (iv == 10) ? Tf : ts_step * (float)iv;
        for (int it = 0; it < 64; ++it) {
            const float remaining = t_target - t;
            if (remaining <= 1e-12f) break;
            const float h = fminf(dt, fmaxf(remaining, 0.0f));

            float k2 = f(y + h * (A21f * k1));
            float k3 = f(y + h * (A31f * k1 + A32f * k2));
            float k4 = f(y + h * (A41f * k1 + A42f * k2 + A43f * k3));
            float k5 = f(y + h * (A51f * k1 + A52f * k2 + A53f * k3 + A54f * k4));
            float k6 = f(y + h * (A61f * k1 + A62f * k2 + A63f * k3 + A64f * k4 + A65f * k5));
            float y5 = y + h * (B1f * k1 + B2f * k2 + B3f * k3 + B4f * k4 + B5f * k5 + B6f * k6);
            float k7 = f(y5);
            float err = h * (E1f * k1 + E2f * k2 + E3f * k3 + E4f * k4 + E5f * k5 + E6f * k6 + E7f * k7);

            float scale = 1e-6f + 1e-3f * fmaxf(fabsf(y), fabsf(y5));
            float r = err / scale;
            float s = r * r;
#pragma unroll
            for (int m = 32; m >= 1; m >>= 1) s += __shfl_xor(s, m);
            float enorm = fmaxf(sqrtf(s * (1.0f / 64.0f)), 1e-10f);

            bool accept = enorm <= 1.0f;
            float fac = 0.9f * exp2f(-0.2f * __log2f(enorm));  // 0.9 * enorm^-0.2
            fac = fminf(fmaxf(fac, 0.1f), 5.0f);

            if (accept) { t += h; y = y5; k1 = k7; }
            dt = fmaxf(h * fac, 1e-8f);
            ++n;
        }
        out[traj * 704 + iv * 64 + lane] = y;
    }

    if (lane == 0) atomicAdd(out + (out_size - 1), (float)n);
}

__global__ void init_n(float* p) { *p = 0.0f; }

extern "C" void kernel_launch(void* const* d_in, const int* in_sizes, int n_in,
                              void* d_out, int out_size, void* d_ws, size_t ws_size,
                              hipStream_t stream) {
    const float* x0s = (const float*)d_in[0];
    const float* W1  = (const float*)d_in[1];
    const float* b1  = (const float*)d_in[2];
    const float* W2  = (const float*)d_in[3];
    const float* b2  = (const float*)d_in[4];
    const float* W3  = (const float*)d_in[5];
    const float* b3  = (const float*)d_in[6];
    const void*  Tp  = d_in[7];
    float* out = (float*)d_out;

    const int B = in_sizes[0] / 64;
    const int grid = (B + WPB - 1) / WPB;

    init_n<<<1, 1, 0, stream>>>(out + (out_size - 1));
    ode_kernel<<<grid, 256, 0, stream>>>(x0s, W1, b1, W2, b2, W3, b3, Tp,
                                         out, out_size, B);
}